// Round 1
// baseline (2163.780 us; speedup 1.0000x reference)
//
#include <hip/hip_runtime.h>

#define DIMS   256
#define KCODES 8192
#define NTOK   32768
#define TM     128   // tokens per block
#define TN     128   // codes per tile
#define TD     32    // dim chunk

// c2[k] = sum_d codebook[k][d]^2  (one wave per row)
__global__ __launch_bounds__(64) void c2_kernel(const float* __restrict__ cb,
                                                float* __restrict__ c2) {
    int row  = blockIdx.x;
    int lane = threadIdx.x;                      // 0..63, DIMS/4 == 64
    float4 v = *(const float4*)(cb + (size_t)row * DIMS + (size_t)lane * 4);
    float s = v.x * v.x + v.y * v.y + v.z * v.z + v.w * v.w;
#pragma unroll
    for (int off = 32; off > 0; off >>= 1) s += __shfl_down(s, off);
    if (lane == 0) c2[row] = s;
}

// Fused distance + argmin + gather. Grid: NTOK/TM blocks of 256 threads.
__global__ __launch_bounds__(256) void vq_kernel(const float* __restrict__ h,
                                                 const float* __restrict__ cb,
                                                 const float* __restrict__ c2,
                                                 float* __restrict__ out_q,
                                                 float* __restrict__ out_idx) {
    __shared__ float Hs[TD][TM];
    __shared__ float Cs[TD][TN];
    __shared__ float red_v[TM][16];
    __shared__ int   red_i[TM][16];
    __shared__ int   final_idx[TM];

    const int tid = threadIdx.x;
    const int tx  = tid & 15;        // code group
    const int ty  = tid >> 4;        // token group
    const int tokBase = blockIdx.x * TM;

    float bestv[8];
    int   besti[8];
#pragma unroll
    for (int i = 0; i < 8; i++) { bestv[i] = 3.4e38f; besti[i] = 0; }

    const int lr = tid >> 3;   // 0..31 : row within 32-row load slab
    const int lq = tid & 7;    // 0..7  : float4 column within TD chunk

    for (int ct = 0; ct < KCODES; ct += TN) {
        float acc[8][8];
#pragma unroll
        for (int i = 0; i < 8; i++)
#pragma unroll
            for (int j = 0; j < 8; j++) acc[i][j] = 0.f;

        for (int dc = 0; dc < DIMS; dc += TD) {
            __syncthreads();
            // stage Hs (transposed) and Cs (transposed)
#pragma unroll
            for (int rr = 0; rr < TM; rr += 32) {
                int r = lr + rr;
                float4 v = *(const float4*)(h + (size_t)(tokBase + r) * DIMS + dc + lq * 4);
                Hs[lq * 4 + 0][r] = v.x;
                Hs[lq * 4 + 1][r] = v.y;
                Hs[lq * 4 + 2][r] = v.z;
                Hs[lq * 4 + 3][r] = v.w;
                float4 w = *(const float4*)(cb + (size_t)(ct + r) * DIMS + dc + lq * 4);
                Cs[lq * 4 + 0][r] = w.x;
                Cs[lq * 4 + 1][r] = w.y;
                Cs[lq * 4 + 2][r] = w.z;
                Cs[lq * 4 + 3][r] = w.w;
            }
            __syncthreads();
#pragma unroll
            for (int d = 0; d < TD; d++) {
                float a[8], b[8];
#pragma unroll
                for (int i = 0; i < 8; i++) a[i] = Hs[d][ty * 8 + i];
#pragma unroll
                for (int j = 0; j < 8; j++) b[j] = Cs[d][tx * 8 + j];
#pragma unroll
                for (int i = 0; i < 8; i++)
#pragma unroll
                    for (int j = 0; j < 8; j++) acc[i][j] += a[i] * b[j];
            }
        }
        // score: dist-relevant part = c2[c] - 2*xc  (x2 constant per token)
#pragma unroll
        for (int j = 0; j < 8; j++) {
            int c = ct + tx * 8 + j;
            float cc = c2[c];
#pragma unroll
            for (int i = 0; i < 8; i++) {
                float s = cc - 2.f * acc[i][j];
                if (s < bestv[i]) { bestv[i] = s; besti[i] = c; }  // strict < keeps first min
            }
        }
    }

    // cross-thread (tx) reduction per token row, tie-break to lowest index
#pragma unroll
    for (int i = 0; i < 8; i++) {
        red_v[ty * 8 + i][tx] = bestv[i];
        red_i[ty * 8 + i][tx] = besti[i];
    }
    __syncthreads();
    if (tid < TM) {
        float bv = red_v[tid][0];
        int   bi = red_i[tid][0];
#pragma unroll
        for (int x = 1; x < 16; x++) {
            float v = red_v[tid][x];
            int   ii = red_i[tid][x];
            if (v < bv || (v == bv && ii < bi)) { bv = v; bi = ii; }
        }
        final_idx[tid] = bi;
        out_idx[tokBase + tid] = (float)bi;
    }
    __syncthreads();

    // gather q rows from codebook
    for (int e = tid; e < TM * (DIMS / 4); e += 256) {
        int r  = e >> 6;          // token row in tile
        int c4 = e & 63;          // float4 index in row
        int idx = final_idx[r];
        float4 v = *(const float4*)(cb + (size_t)idx * DIMS + c4 * 4);
        *(float4*)(out_q + (size_t)(tokBase + r) * DIMS + c4 * 4) = v;
    }
}

extern "C" void kernel_launch(void* const* d_in, const int* in_sizes, int n_in,
                              void* d_out, int out_size, void* d_ws, size_t ws_size,
                              hipStream_t stream) {
    const float* h  = (const float*)d_in[0];   // [32768, 256]
    const float* cb = (const float*)d_in[1];   // [8192, 256]
    float* out_q   = (float*)d_out;            // [32768*256]
    float* out_idx = (float*)d_out + (size_t)NTOK * DIMS;  // [32768] as float
    float* c2 = (float*)d_ws;                  // [8192]

    c2_kernel<<<KCODES, 64, 0, stream>>>(cb, c2);
    vq_kernel<<<NTOK / TM, 256, 0, stream>>>(h, cb, c2, out_q, out_idx);
}

// Round 2
// 1252.821 us; speedup vs baseline: 1.7271x; 1.7271x over previous
//
#include <hip/hip_runtime.h>

typedef short short8 __attribute__((ext_vector_type(8)));
typedef float f32x4 __attribute__((ext_vector_type(4)));

#define DIMS   256
#define KCODES 8192
#define NTOK   32768
#define BM     128
#define BN     128
#define NTILES (KCODES / BN)   // 64
#define LROW   264             // padded LDS row stride in bf16 elems (+8 -> 2-way bank = free)
#define MARGIN 2.5f            // covers bf16 dot error (~29 sigma) + fp16 tile-min rounding

__device__ __forceinline__ unsigned short f2bf(float f) {
    unsigned u = __builtin_bit_cast(unsigned, f);
    unsigned r = (u + 0x7FFFu + ((u >> 16) & 1u)) >> 16;   // RNE
    return (unsigned short)r;
}
__device__ __forceinline__ unsigned fenc(float f) {        // order-preserving float->uint
    unsigned u = __builtin_bit_cast(unsigned, f);
    return ((int)u >= 0) ? (u | 0x80000000u) : ~u;
}

// c2[k] = sum_d cb[k][d]^2
__global__ __launch_bounds__(64) void c2_kernel(const float* __restrict__ cb,
                                                float* __restrict__ c2) {
    int row = blockIdx.x, lane = threadIdx.x;
    float4 v = *(const float4*)(cb + (size_t)row * DIMS + (size_t)lane * 4);
    float s = v.x * v.x + v.y * v.y + v.z * v.z + v.w * v.w;
#pragma unroll
    for (int off = 32; off > 0; off >>= 1) s += __shfl_down(s, off);
    if (lane == 0) c2[row] = s;
}

// cb fp32 -> bf16 (workspace)
__global__ __launch_bounds__(64) void conv_kernel(const float* __restrict__ cb,
                                                  unsigned short* __restrict__ cbbf) {
    int row = blockIdx.x, lane = threadIdx.x;
    float4 v = *(const float4*)(cb + (size_t)row * DIMS + (size_t)lane * 4);
    ushort4 s;
    s.x = f2bf(v.x); s.y = f2bf(v.y); s.z = f2bf(v.z); s.w = f2bf(v.w);
    *(ushort4*)(cbbf + (size_t)row * DIMS + (size_t)lane * 4) = s;
}

template <bool WSBF>
__global__ __launch_bounds__(256) void vq_main(const float* __restrict__ h,
                                               const float* __restrict__ cb,
                                               const unsigned short* __restrict__ cbbf,
                                               const float* __restrict__ c2g,
                                               float* __restrict__ out_q,
                                               float* __restrict__ out_idx) {
    __shared__ unsigned short As[BM * LROW];     // 67584 B
    __shared__ unsigned short Bs[BN * LROW];     // 67584 B
    __shared__ _Float16 tmin[NTILES * BM];       // 16384 B
    __shared__ float red[2][BM];                 // 1024 B
    __shared__ float mrun[BM];
    __shared__ float c2s[BN];
    __shared__ float hbuf[4][DIMS];              // 4096 B
    __shared__ unsigned list[512];               // 2048 B
    __shared__ unsigned long long best64[BM];    // 1024 B
    __shared__ int fin[BM];
    __shared__ int cnt;

    const int tid  = threadIdx.x;
    const int lane = tid & 63;
    const int wave = tid >> 6;
    const int l15  = lane & 15;
    const int quad = lane >> 4;
    const int wm   = wave >> 1, wn = wave & 1;
    const int tokBase = blockIdx.x * BM;

    if (tid < BM) { mrun[tid] = 3.4e38f; best64[tid] = ~0ULL; }
    if (tid == 0) cnt = 0;

    // ---- stage A slab (h, fp32 -> bf16), once: 128x256 = 4096 8-elem chunks ----
#pragma unroll
    for (int i = 0; i < 16; i++) {
        int ch = tid + i * 256;
        int row = ch >> 5, c8 = ch & 31;
        const float4* src = (const float4*)(h + (size_t)(tokBase + row) * DIMS + c8 * 8);
        float4 v0 = src[0], v1 = src[1];
        short8 s;
        s[0] = f2bf(v0.x); s[1] = f2bf(v0.y); s[2] = f2bf(v0.z); s[3] = f2bf(v0.w);
        s[4] = f2bf(v1.x); s[5] = f2bf(v1.y); s[6] = f2bf(v1.z); s[7] = f2bf(v1.w);
        *(short8*)&As[row * LROW + c8 * 8] = s;
    }

    // ---- K-tile loop over codebook ----
    for (int t = 0; t < NTILES; t++) {
        const int ct = t * BN;
        __syncthreads();   // (a) prev compute/combine done before overwriting Bs/red

        // stage B tile (codes ct..ct+127)
#pragma unroll
        for (int i = 0; i < 16; i++) {
            int ch = tid + i * 256;
            int row = ch >> 5, c8 = ch & 31;
            short8 s;
            if constexpr (WSBF) {
                s = *(const short8*)(cbbf + (size_t)(ct + row) * DIMS + c8 * 8);
            } else {
                const float4* src = (const float4*)(cb + (size_t)(ct + row) * DIMS + c8 * 8);
                float4 v0 = src[0], v1 = src[1];
                s[0] = f2bf(v0.x); s[1] = f2bf(v0.y); s[2] = f2bf(v0.z); s[3] = f2bf(v0.w);
                s[4] = f2bf(v1.x); s[5] = f2bf(v1.y); s[6] = f2bf(v1.z); s[7] = f2bf(v1.w);
            }
            *(short8*)&Bs[row * LROW + c8 * 8] = s;
        }
        if (tid < BN) c2s[tid] = c2g[ct + tid];
        __syncthreads();   // (b) staging visible

        // MFMA: wave (wm,wn) computes tokens [wm*64,+64) x codes [wn*64,+64)
        f32x4 acc[4][4];
#pragma unroll
        for (int i = 0; i < 4; i++)
#pragma unroll
            for (int j = 0; j < 4; j++) acc[i][j] = (f32x4){0.f, 0.f, 0.f, 0.f};

#pragma unroll
        for (int kk = 0; kk < 8; kk++) {
            short8 a[4], b[4];
#pragma unroll
            for (int i = 0; i < 4; i++)
                a[i] = *(const short8*)&As[(wm * 64 + i * 16 + l15) * LROW + kk * 32 + quad * 8];
#pragma unroll
            for (int j = 0; j < 4; j++)
                b[j] = *(const short8*)&Bs[(wn * 64 + j * 16 + l15) * LROW + kk * 32 + quad * 8];
#pragma unroll
            for (int i = 0; i < 4; i++)
#pragma unroll
                for (int j = 0; j < 4; j++)
                    acc[i][j] = __builtin_amdgcn_mfma_f32_16x16x32_bf16(a[i], b[j], acc[i][j], 0, 0, 0);
        }

        // scores: s = c2[code] - 2*xc ; per-token min over this tile's 128 codes
        float vmin[4][4];
#pragma unroll
        for (int i = 0; i < 4; i++)
#pragma unroll
            for (int r = 0; r < 4; r++) vmin[i][r] = 3.4e38f;
#pragma unroll
        for (int j = 0; j < 4; j++) {
            float cc = c2s[wn * 64 + j * 16 + l15];
#pragma unroll
            for (int i = 0; i < 4; i++)
#pragma unroll
                for (int r = 0; r < 4; r++) {
                    float s = cc - 2.f * acc[i][j][r];
                    vmin[i][r] = fminf(vmin[i][r], s);
                }
        }
        // min over the 16 cols (low 4 lane bits)
#pragma unroll
        for (int m = 1; m < 16; m <<= 1)
#pragma unroll
            for (int i = 0; i < 4; i++)
#pragma unroll
                for (int r = 0; r < 4; r++)
                    vmin[i][r] = fminf(vmin[i][r], __shfl_xor(vmin[i][r], m));
        if (l15 == 0) {
#pragma unroll
            for (int i = 0; i < 4; i++) {
                float4 w4 = make_float4(vmin[i][0], vmin[i][1], vmin[i][2], vmin[i][3]);
                *(float4*)&red[wn][wm * 64 + i * 16 + quad * 4] = w4;
            }
        }
        __syncthreads();   // (c) red visible
        if (tid < BM) {
            float v = fminf(red[0][tid], red[1][tid]);
            _Float16 hv = (_Float16)v;
            tmin[t * BM + tid] = hv;
            mrun[tid] = fminf(mrun[tid], (float)hv);
        }
    }
    __syncthreads();

    // ---- collect candidate (token, tile) pairs ----
    for (int p = tid; p < BM * NTILES; p += 256) {
        int tok = p >> 6, t = p & 63;
        if ((float)tmin[t * BM + tok] <= mrun[tok] + MARGIN) {
            int pos = atomicAdd(&cnt, 1);
            if (pos < 512) list[pos] = (unsigned)((tok << 6) | t);
        }
    }
    __syncthreads();

    // ---- exact fp32 rescore of candidates ----
    int n = cnt; if (n > 512) n = 512;
    for (int p = wave; p < n; p += 4) {
        unsigned e = list[p];
        int tok = (int)(e >> 6), t = (int)(e & 63);
        float4 hv4 = *(const float4*)(h + (size_t)(tokBase + tok) * DIMS + lane * 4);
        *(float4*)&hbuf[wave][lane * 4] = hv4;
        const float4* hrow = (const float4*)&hbuf[wave][0];
#pragma unroll
        for (int half = 0; half < 2; half++) {
            int code = t * BN + half * 64 + lane;
            const float4* crow = (const float4*)(cb + (size_t)code * DIMS);
            float dot = 0.f;
#pragma unroll 8
            for (int d = 0; d < 64; d++) {
                float4 c = crow[d];
                float4 hh = hrow[d];
                dot = fmaf(c.x, hh.x, dot);
                dot = fmaf(c.y, hh.y, dot);
                dot = fmaf(c.z, hh.z, dot);
                dot = fmaf(c.w, hh.w, dot);
            }
            float s = c2g[code] - 2.f * dot;
            unsigned long long pk = ((unsigned long long)fenc(s) << 32) | (unsigned)code;
            atomicMin(&best64[tok], pk);
        }
    }
    __syncthreads();

    // ---- finalize: idx + gather q ----
    if (tid < BM) {
        int idx = (int)(best64[tid] & 0xFFFFFFFFULL);
        fin[tid] = idx;
        out_idx[tokBase + tid] = (float)idx;
    }
    __syncthreads();
    for (int e = tid; e < BM * (DIMS / 4); e += 256) {
        int r = e >> 6, c4 = e & 63;
        float4 v = *(const float4*)(cb + (size_t)fin[r] * DIMS + c4 * 4);
        *(float4*)(out_q + (size_t)(tokBase + r) * DIMS + c4 * 4) = v;
    }
}

extern "C" void kernel_launch(void* const* d_in, const int* in_sizes, int n_in,
                              void* d_out, int out_size, void* d_ws, size_t ws_size,
                              hipStream_t stream) {
    const float* h  = (const float*)d_in[0];   // [32768, 256]
    const float* cb = (const float*)d_in[1];   // [8192, 256]
    float* out_q   = (float*)d_out;
    float* out_idx = (float*)d_out + (size_t)NTOK * DIMS;

    float* c2 = (float*)d_ws;                                  // 32 KB
    unsigned short* cbbf = (unsigned short*)((char*)d_ws + 32768);  // 4 MB
    const size_t needed = 32768 + (size_t)KCODES * DIMS * 2;

    c2_kernel<<<KCODES, 64, 0, stream>>>(cb, c2);
    if (ws_size >= needed) {
        conv_kernel<<<KCODES, 64, 0, stream>>>(cb, cbbf);
        vq_main<true><<<NTOK / BM, 256, 0, stream>>>(h, cb, cbbf, c2, out_q, out_idx);
    } else {
        vq_main<false><<<NTOK / BM, 256, 0, stream>>>(h, cb, (const unsigned short*)nullptr, c2, out_q, out_idx);
    }
}

// Round 3
// 464.891 us; speedup vs baseline: 4.6544x; 2.6949x over previous
//
#include <hip/hip_runtime.h>

typedef short short8 __attribute__((ext_vector_type(8)));
typedef float f32x4 __attribute__((ext_vector_type(4)));

#define DIMS   256
#define KCODES 8192
#define NTOK   32768
#define BM     128
#define BN     128
#define NTILES 64
#define LROW   264      // LDS row stride bf16 elems: 528B -> stride 4 dw mod 32 -> 2-way (free)
#define MARGIN 0.75f    // ~18 sigma of bf16 score error (sigma ~0.04); Hoeffding bound exp(-165)
#define CAP    4096

__device__ __forceinline__ unsigned short f2bf(float f) {
    unsigned u = __builtin_bit_cast(unsigned, f);
    unsigned r = (u + 0x7FFFu + ((u >> 16) & 1u)) >> 16;   // RNE
    return (unsigned short)r;
}
__device__ __forceinline__ unsigned fenc(float f) {        // order-preserving float->uint
    unsigned u = __builtin_bit_cast(unsigned, f);
    return ((int)u >= 0) ? (u | 0x80000000u) : ~u;
}

// fused: c2[k] = ||cb[k]||^2 (fp32) and optional fp32->bf16 codebook convert.
// one wave per code row, 4 rows per block.
__global__ __launch_bounds__(256) void prep_kernel(const float* __restrict__ cb,
                                                   float* __restrict__ c2,
                                                   unsigned short* __restrict__ cbbf,
                                                   int do_conv) {
    int row  = blockIdx.x * 4 + (threadIdx.x >> 6);
    int lane = threadIdx.x & 63;
    float4 v = *(const float4*)(cb + (size_t)row * DIMS + (size_t)lane * 4);
    if (do_conv) {
        ushort4 s;
        s.x = f2bf(v.x); s.y = f2bf(v.y); s.z = f2bf(v.z); s.w = f2bf(v.w);
        *(ushort4*)(cbbf + (size_t)row * DIMS + (size_t)lane * 4) = s;
    }
    float s = v.x * v.x + v.y * v.y + v.z * v.z + v.w * v.w;
#pragma unroll
    for (int off = 32; off > 0; off >>= 1) s += __shfl_down(s, off);
    if (lane == 0) c2[row] = s;
}

template <bool WSBF>
__global__ __launch_bounds__(512, 2) void vq_main(const float* __restrict__ h,
                                                  const float* __restrict__ cb,
                                                  const unsigned short* __restrict__ cbbf,
                                                  const float* __restrict__ c2g,
                                                  float* __restrict__ out_q,
                                                  float* __restrict__ out_idx) {
    __shared__ unsigned short Bs[BN * LROW];     // 67584 B
    __shared__ float red[4][BM];                 // 2048 B
    __shared__ float mrun[BM];
    __shared__ float c2s[BN];
    __shared__ unsigned list[CAP];               // 16384 B
    __shared__ unsigned long long best64[BM];
    __shared__ int fin[BM];
    __shared__ int cnt;

    const int tid  = threadIdx.x;
    const int lane = tid & 63;
    const int wave = tid >> 6;
    const int l15  = lane & 15;
    const int quad = lane >> 4;
    const int wm   = wave >> 2;      // 0..1 : token half
    const int wn   = wave & 3;       // 0..3 : 32-code stripe
    const int tokBase = blockIdx.x * BM;

    if (tid < BM) { mrun[tid] = 3.4e38f; best64[tid] = ~0ULL; }
    if (tid == 0) cnt = 0;

    // ---- A fragments in registers: wave's 64 tokens x 256 dims (bf16), 128 VGPR ----
    short8 afr[4][8];
#pragma unroll
    for (int i = 0; i < 4; i++) {
        const float* base = h + (size_t)(tokBase + wm * 64 + i * 16 + l15) * DIMS + quad * 8;
#pragma unroll
        for (int kk = 0; kk < 8; kk++) {
            float4 v0 = *(const float4*)(base + kk * 32);
            float4 v1 = *(const float4*)(base + kk * 32 + 4);
            short8 s;
            s[0] = f2bf(v0.x); s[1] = f2bf(v0.y); s[2] = f2bf(v0.z); s[3] = f2bf(v0.w);
            s[4] = f2bf(v1.x); s[5] = f2bf(v1.y); s[6] = f2bf(v1.z); s[7] = f2bf(v1.w);
            afr[i][kk] = s;
        }
    }

    // ---- B-tile register prefetch: 8 short8 chunks per thread (64KB/512thr) ----
    short8 pf[8];
    auto load_pf = [&](int t) {
#pragma unroll
        for (int n = 0; n < 8; n++) {
            int ch = tid + n * 512;
            int row = ch >> 5, c8 = ch & 31;
            if constexpr (WSBF) {
                pf[n] = *(const short8*)(cbbf + (size_t)(t * BN + row) * DIMS + c8 * 8);
            } else {
                const float4* src = (const float4*)(cb + (size_t)(t * BN + row) * DIMS + c8 * 8);
                float4 v0 = src[0], v1 = src[1];
                short8 s;
                s[0] = f2bf(v0.x); s[1] = f2bf(v0.y); s[2] = f2bf(v0.z); s[3] = f2bf(v0.w);
                s[4] = f2bf(v1.x); s[5] = f2bf(v1.y); s[6] = f2bf(v1.z); s[7] = f2bf(v1.w);
                pf[n] = s;
            }
        }
    };
    load_pf(0);

    // ---- main loop: 64 tiles + redo of tile 0 (emission vs final running min) ----
#pragma unroll 1
    for (int it = 0; it <= NTILES; ++it) {
        const int t = (it == NTILES) ? 0 : it;
        __syncthreads();   // (a) Bs/c2s reuse safe; mrun updates of it-1 visible
#pragma unroll
        for (int n = 0; n < 8; n++) {
            int ch = tid + n * 512;
            int row = ch >> 5, c8 = ch & 31;
            *(short8*)&Bs[row * LROW + c8 * 8] = pf[n];
        }
        if (tid < BN) c2s[tid] = c2g[t * BN + tid];
        if (it < NTILES) load_pf((it + 1 == NTILES) ? 0 : it + 1);   // hidden under MFMA
        __syncthreads();   // (b) staging visible

        // MFMA: 4 row-blocks x 2 col-blocks of 16x16, K=256
        f32x4 acc[4][2];
#pragma unroll
        for (int i = 0; i < 4; i++) { acc[i][0] = (f32x4){0,0,0,0}; acc[i][1] = (f32x4){0,0,0,0}; }
#pragma unroll
        for (int kk = 0; kk < 8; kk++) {
            short8 b0 = *(const short8*)&Bs[(wn * 32 + l15) * LROW + kk * 32 + quad * 8];
            short8 b1 = *(const short8*)&Bs[(wn * 32 + 16 + l15) * LROW + kk * 32 + quad * 8];
#pragma unroll
            for (int i = 0; i < 4; i++) {
                acc[i][0] = __builtin_amdgcn_mfma_f32_16x16x32_bf16(afr[i][kk], b0, acc[i][0], 0, 0, 0);
                acc[i][1] = __builtin_amdgcn_mfma_f32_16x16x32_bf16(afr[i][kk], b1, acc[i][1], 0, 0, 0);
            }
        }

        // scores, candidate emission (lagged threshold), per-wave tile-min
        float cc0 = c2s[wn * 32 + l15];
        float cc1 = c2s[wn * 32 + 16 + l15];
        int code0 = t * BN + wn * 32 + l15;
#pragma unroll
        for (int i = 0; i < 4; i++) {
            int tokb = wm * 64 + i * 16 + quad * 4;
            float thr0 = 0, thr1 = 0, thr2 = 0, thr3 = 0;
            if (it > 0) {
                thr0 = mrun[tokb + 0] + MARGIN; thr1 = mrun[tokb + 1] + MARGIN;
                thr2 = mrun[tokb + 2] + MARGIN; thr3 = mrun[tokb + 3] + MARGIN;
            }
            float vm0 = 3.4e38f, vm1 = 3.4e38f, vm2 = 3.4e38f, vm3 = 3.4e38f;
#pragma unroll
            for (int j = 0; j < 2; j++) {
                float cc = j ? cc1 : cc0;
                int code = j ? code0 + 16 : code0;
                float s0 = fmaf(-2.f, acc[i][j][0], cc);
                float s1 = fmaf(-2.f, acc[i][j][1], cc);
                float s2 = fmaf(-2.f, acc[i][j][2], cc);
                float s3 = fmaf(-2.f, acc[i][j][3], cc);
                vm0 = fminf(vm0, s0); vm1 = fminf(vm1, s1);
                vm2 = fminf(vm2, s2); vm3 = fminf(vm3, s3);
                if (it > 0) {
                    if (s0 <= thr0) { int p = atomicAdd(&cnt, 1); if (p < CAP) list[p] = (unsigned)(((tokb + 0) << 13) | code); }
                    if (s1 <= thr1) { int p = atomicAdd(&cnt, 1); if (p < CAP) list[p] = (unsigned)(((tokb + 1) << 13) | code); }
                    if (s2 <= thr2) { int p = atomicAdd(&cnt, 1); if (p < CAP) list[p] = (unsigned)(((tokb + 2) << 13) | code); }
                    if (s3 <= thr3) { int p = atomicAdd(&cnt, 1); if (p < CAP) list[p] = (unsigned)(((tokb + 3) << 13) | code); }
                }
            }
            if (it < NTILES) {
#pragma unroll
                for (int m = 1; m < 16; m <<= 1) {
                    vm0 = fminf(vm0, __shfl_xor(vm0, m));
                    vm1 = fminf(vm1, __shfl_xor(vm1, m));
                    vm2 = fminf(vm2, __shfl_xor(vm2, m));
                    vm3 = fminf(vm3, __shfl_xor(vm3, m));
                }
                if (l15 == 0) {
                    float4 w = make_float4(vm0, vm1, vm2, vm3);
                    *(float4*)&red[wn][tokb] = w;
                }
            }
        }
        if (it < NTILES) {
            __syncthreads();   // (c) red visible
            if (tid < BM) {    // single writer per token
                float m = fminf(fminf(red[0][tid], red[1][tid]), fminf(red[2][tid], red[3][tid]));
                mrun[tid] = fminf(mrun[tid], m);
            }
        }
    }
    __syncthreads();   // list/cnt final

    // ---- exact fp32 rescore of candidates: one wave-dot each (coalesced) ----
    int n = cnt; if (n > CAP) n = CAP;
    for (int p = wave; p < n; p += 8) {
        unsigned e = list[p];
        int tok = (int)(e >> 13), code = (int)(e & 8191);
        float4 hv = *(const float4*)(h + (size_t)(tokBase + tok) * DIMS + lane * 4);
        float4 cv = *(const float4*)(cb + (size_t)code * DIMS + lane * 4);
        float d = hv.x * cv.x + hv.y * cv.y + hv.z * cv.z + hv.w * cv.w;
#pragma unroll
        for (int m = 1; m < 64; m <<= 1) d += __shfl_xor(d, m);
        float s = c2g[code] - 2.f * d;
        if (lane == 0)
            atomicMin(&best64[tok], ((unsigned long long)fenc(s) << 32) | (unsigned)code);
    }
    __syncthreads();

    if (tid < BM) {
        int idx = (int)(best64[tid] & 0xFFFFFFFFULL);
        fin[tid] = idx;
        out_idx[tokBase + tid] = (float)idx;
    }
    __syncthreads();
#pragma unroll
    for (int e = tid; e < BM * (DIMS / 4); e += 512) {
        int r = e >> 6, c4 = e & 63;
        float4 v = *(const float4*)(cb + (size_t)fin[r] * DIMS + c4 * 4);
        *(float4*)(out_q + (size_t)(tokBase + r) * DIMS + c4 * 4) = v;
    }
}

extern "C" void kernel_launch(void* const* d_in, const int* in_sizes, int n_in,
                              void* d_out, int out_size, void* d_ws, size_t ws_size,
                              hipStream_t stream) {
    const float* h  = (const float*)d_in[0];   // [32768, 256]
    const float* cb = (const float*)d_in[1];   // [8192, 256]
    float* out_q   = (float*)d_out;
    float* out_idx = (float*)d_out + (size_t)NTOK * DIMS;

    float* c2 = (float*)d_ws;                                       // 32 KB
    unsigned short* cbbf = (unsigned short*)((char*)d_ws + 32768);  // 4 MB
    const size_t needed = 32768 + (size_t)KCODES * DIMS * 2;
    const int wsbf = (ws_size >= needed) ? 1 : 0;

    prep_kernel<<<KCODES / 4, 256, 0, stream>>>(cb, c2, cbbf, wsbf);
    if (wsbf)
        vq_main<true><<<NTOK / BM, 512, 0, stream>>>(h, cb, cbbf, c2, out_q, out_idx);
    else
        vq_main<false><<<NTOK / BM, 512, 0, stream>>>(h, cb, (const unsigned short*)nullptr, c2, out_q, out_idx);
}